// Round 13
// baseline (124.259 us; speedup 1.0000x reference)
//
#include <hip/hip_runtime.h>
#include <math.h>

// Tropical bottleneck network — fully fused single kernel, packed f16,
// k-slot-vectorized inner loop.
// Each block owns 4 batch cols; all 12 stages run locally with LDS barriers.
// Activations in LDS, layout [K/8][4][8]: h8 = 8 consecutive k of ONE batch col.
// Weights pre-chunked Wc[K/8][R][8] (h8 = 8 k of one row), streamed from L2.
// Inner: acc[r][b] (h8 over k-slots) = rdv8(acc, x8[b] + w8[r]) — pure
// v_pk_add_f16 / v_pk_min/max_f16, no splats; x via 4 broadcast ds_read_b128
// per wave-chunk; W via coalesced 16B global loads. Reduce h8->scalar in
// epilogue; KS-way K-split combined through padded LDS `part`.

typedef _Float16 h2 __attribute__((ext_vector_type(2)));
typedef _Float16 h4 __attribute__((ext_vector_type(4)));
typedef _Float16 h8 __attribute__((ext_vector_type(8)));

template<int M, typename V> __device__ __forceinline__ V rdv(V a, V b) {
    if constexpr (M) return __builtin_elementwise_max(a, b);
    else             return __builtin_elementwise_min(a, b);
}
template<int M> __device__ __forceinline__ _Float16 rd1(_Float16 a, _Float16 b) {
    if constexpr (M) return a > b ? a : b;
    else             return a < b ? a : b;
}
__device__ __forceinline__ h4 lo4(h8 v){ return __builtin_shufflevector(v,v,0,1,2,3); }
__device__ __forceinline__ h4 hi4(h8 v){ return __builtin_shufflevector(v,v,4,5,6,7); }
__device__ __forceinline__ h2 lo2(h4 v){ return __builtin_shufflevector(v,v,0,1); }
__device__ __forceinline__ h2 hi2(h4 v){ return __builtin_shufflevector(v,v,2,3); }
template<int M> __device__ __forceinline__ _Float16 red81(h8 v) {
    h4 m4 = rdv<M>(lo4(v), hi4(v));
    h2 m2 = rdv<M>(lo2(m4), hi2(m4));
    return rd1<M>(m2[0], m2[1]);
}

struct NetP {
    const float* x;
    const h8 *w11, *w12, *w21, *w22, *w31, *w32;
    const h8 *w41, *w42, *sw1, *sw2, *scw1, *scw2;
    const _Float16 *b12, *b22, *b32, *b42, *sb2, *scb2;
    float* out;
};

// LDS activation addressing: value (row k, batch bb) lives at
//   (k>>3)*32 + bb*8 + (k&7)   (halfs)
__device__ __forceinline__ int aidx(int k, int bb) {
    return ((k >> 3) << 5) + (bb << 3) + (k & 7);
}

#define PST 18   // padded part stride (halfs) per row-group — kills bank conflicts

template<int ISMAX, int R, int K, bool GOUT>
__device__ __forceinline__ void stage(
    const h8* __restrict__ Wc,            // [K/8][R] h8
    const _Float16* __restrict__ bias,    // f16 global (ISMAX) or nullptr
    const _Float16* __restrict__ X,       // LDS [K/8][4][8]
    const _Float16* __restrict__ E1,      // LDS min-combine or nullptr
    const _Float16* __restrict__ E2,      // LDS max-combine or nullptr
    _Float16* __restrict__ Y,             // LDS out (unless GOUT)
    float* __restrict__ gout, int b0,
    _Float16* __restrict__ part)
{
    constexpr int NRG = R / 4;            // row-groups (4 rows/thread, stride NRG)
    constexpr int KS  = 512 / NRG;        // K-split ways
    constexpr int NC  = K / (8 * KS);     // chunks per thread
    const int tid  = threadIdx.x;
    const int rowg = tid & (NRG - 1);
    const int kq   = tid / NRG;           // wave-uniform
    const int kc0  = kq * NC;

    const h8* X8 = (const h8*)X;

    h8 acc[4][4];                         // [row i][batch bb], h8 over k-slots
    {   // peel first chunk: init, no +-INF
        h8 xv[4], wv[4];
#pragma unroll
        for (int bb = 0; bb < 4; ++bb) xv[bb] = X8[kc0 * 4 + bb];
#pragma unroll
        for (int i = 0; i < 4; ++i) wv[i] = Wc[(size_t)kc0 * R + rowg + i * NRG];
#pragma unroll
        for (int i = 0; i < 4; ++i)
#pragma unroll
            for (int bb = 0; bb < 4; ++bb) acc[i][bb] = xv[bb] + wv[i];
    }
#pragma unroll 2
    for (int kc = kc0 + 1; kc < kc0 + NC; ++kc) {
        h8 xv[4], wv[4];
#pragma unroll
        for (int bb = 0; bb < 4; ++bb) xv[bb] = X8[kc * 4 + bb];
#pragma unroll
        for (int i = 0; i < 4; ++i) wv[i] = Wc[(size_t)kc * R + rowg + i * NRG];
#pragma unroll
        for (int i = 0; i < 4; ++i)
#pragma unroll
            for (int bb = 0; bb < 4; ++bb)
                acc[i][bb] = rdv<ISMAX>(acc[i][bb], xv[bb] + wv[i]);
    }

    // reduce h8 -> scalar per (row, batch)
    _Float16 v[4][4];
#pragma unroll
    for (int i = 0; i < 4; ++i)
#pragma unroll
        for (int bb = 0; bb < 4; ++bb) v[i][bb] = red81<ISMAX>(acc[i][bb]);

    if (kq) {
        h2* ppw = (h2*)(part + (size_t)(kq - 1) * (NRG * PST) + rowg * PST);
#pragma unroll
        for (int i = 0; i < 4; ++i) {
            h2 t0; t0[0] = v[i][0]; t0[1] = v[i][1];
            h2 t1; t1[0] = v[i][2]; t1[1] = v[i][3];
            ppw[i * 2 + 0] = t0;
            ppw[i * 2 + 1] = t1;
        }
    }
    __syncthreads();
    if (kq == 0) {
#pragma unroll
        for (int qq = 0; qq < KS - 1; ++qq) {
            const h2* q = (const h2*)(part + (size_t)qq * (NRG * PST) + rowg * PST);
#pragma unroll
            for (int i = 0; i < 4; ++i) {
                h2 t0 = q[i * 2], t1 = q[i * 2 + 1];
                v[i][0] = rd1<ISMAX>(v[i][0], t0[0]);
                v[i][1] = rd1<ISMAX>(v[i][1], t0[1]);
                v[i][2] = rd1<ISMAX>(v[i][2], t1[0]);
                v[i][3] = rd1<ISMAX>(v[i][3], t1[1]);
            }
        }
#pragma unroll
        for (int i = 0; i < 4; ++i) {
            const int r = rowg + i * NRG;
            if (ISMAX) {
                _Float16 bi = bias[r];
#pragma unroll
                for (int bb = 0; bb < 4; ++bb) v[i][bb] += bi;
            }
            if (E1) {
#pragma unroll
                for (int bb = 0; bb < 4; ++bb) {
                    _Float16 e = E1[aidx(r, bb)];
                    v[i][bb] = v[i][bb] < e ? v[i][bb] : e;
                }
            }
            if (E2) {
#pragma unroll
                for (int bb = 0; bb < 4; ++bb) {
                    _Float16 e = E2[aidx(r, bb)];
                    v[i][bb] = v[i][bb] > e ? v[i][bb] : e;
                }
            }
            if constexpr (GOUT) {
#pragma unroll
                for (int bb = 0; bb < 4; ++bb)
                    gout[(size_t)(b0 + bb) * 512 + r] = (float)v[i][bb];
            } else {
#pragma unroll
                for (int bb = 0; bb < 4; ++bb) Y[aidx(r, bb)] = v[i][bb];
            }
        }
    }
    __syncthreads();
}

__global__ __launch_bounds__(512) void netf(NetP p)
{
    __shared__ __align__(16) _Float16 X0[1024];                    // 2 KB
    __shared__ __align__(16) _Float16 B0[2048], B1[2048];          // 4 KB each
    __shared__ __align__(16) _Float16 B2[2048], B3[2048];
    __shared__ __align__(16) _Float16 part[7 * 64 * PST];          // 15.75 KB
    const int tid = threadIdx.x;
    const int b0  = blockIdx.x * 4;

    {   // x f32 -> X0 f16, layout [K/8][4][8]
        const int bl = tid >> 7;          // batch col 0..3
        const int kk = tid & 127;         // k-pair index
        float2 xv = *(const float2*)&p.x[(size_t)(b0 + bl) * 256 + kk * 2];
        const int k = kk * 2;
        h2 t; t[0] = (_Float16)xv.x; t[1] = (_Float16)xv.y;
        ((h2*)X0)[aidx(k, bl) >> 1] = t;
    }
    __syncthreads();

    float* o = p.out;
    // bottleneck shortcut first (X0 live only through layer-1)
    stage<0,512,256,false>(p.scw1, nullptr, X0, nullptr, nullptr, B0, o, b0, part);
    stage<1,512,512,false>(p.scw2, p.scb2,  B0, nullptr, nullptr, B1, o, b0, part); // B1=SCout
    // layer 1
    stage<0,256,256,false>(p.w11, nullptr, X0, nullptr, nullptr, B0, o, b0, part);
    stage<1,256,256,false>(p.w12, p.b12,   B0, X0,      nullptr, B2, o, b0, part);
    // layer 2
    stage<0,256,256,false>(p.w21, nullptr, B2, nullptr, nullptr, B0, o, b0, part);
    stage<1,256,256,false>(p.w22, p.b22,   B0, B2,      nullptr, B3, o, b0, part);
    // layer 3
    stage<0,256,256,false>(p.w31, nullptr, B3, nullptr, nullptr, B0, o, b0, part);
    stage<1,256,256,false>(p.w32, p.b32,   B0, B3,      nullptr, B2, o, b0, part); // B2=x3
    // layer 4
    stage<0,512,256,false>(p.w41, nullptr, B2, nullptr, nullptr, B0, o, b0, part); // T1
    stage<0,512,256,false>(p.sw1, nullptr, B2, nullptr, nullptr, B3, o, b0, part); // T2
    stage<1,512,512,false>(p.w42, p.b42,   B0, nullptr, nullptr, B2, o, b0, part); // O4
    // final: max(min(maxbplus(T2,sw2,sb2), O4), SCout) -> global out
    stage<1,512,512,true >(p.sw2, p.sb2,   B3, B2,      B1, nullptr, o, b0, part);
}

// ---- one-time weight prep: f32 [R][K] -> f16 chunked Wc[K/8][R][8] ----
struct CW { const float* s[12]; h8* d[12]; int R[12]; int K[12]; };
__global__ __launch_bounds__(256) void cvtw(CW p)
{
    const int m = blockIdx.y;
    const int R = p.R[m], K = p.K[m];
    const int tilesR = R >> 6;
    const int nt = tilesR * (K >> 6);
    const int t = blockIdx.x;
    if (t >= nt) return;
    const int tr = t % tilesR, tk = t / tilesR;

    __shared__ float s[64][65];
    const int lane = threadIdx.x & 63, ty = threadIdx.x >> 6;
    const float* src = p.s[m];
#pragma unroll
    for (int r = ty; r < 64; r += 4)
        s[r][lane] = src[(size_t)(tr * 64 + r) * K + tk * 64 + lane];
    __syncthreads();
    h8* dst = p.d[m];
#pragma unroll
    for (int c = 0; c < 2; ++c) {
        int cc = ty + c * 4;                 // 0..7
        h8 v;
#pragma unroll
        for (int j = 0; j < 8; ++j) v[j] = (_Float16)s[lane][cc * 8 + j];
        dst[(size_t)(tk * 8 + cc) * R + tr * 64 + lane] = v;
    }
}

struct CB { const float* s[6]; _Float16* d[6]; int n[6]; };
__global__ __launch_bounds__(256) void cvtb(CB p)
{
    for (int m = 0; m < 6; ++m)
        for (int i = threadIdx.x; i < p.n[m]; i += 256)
            p.d[m][i] = (_Float16)p.s[m][i];
}

extern "C" void kernel_launch(void* const* d_in, const int* in_sizes, int n_in,
                              void* d_out, int out_size, void* d_ws, size_t ws_size,
                              hipStream_t stream) {
    (void)in_sizes; (void)n_in; (void)ws_size; (void)out_size;
    const float* fin[19];
    for (int i = 0; i < 19; ++i) fin[i] = (const float*)d_in[i];

    _Float16* hw = (_Float16*)d_ws;

    _Float16* w11c  = hw;
    _Float16* w12c  = hw + 65536;
    _Float16* w21c  = hw + 131072;
    _Float16* w22c  = hw + 196608;
    _Float16* w31c  = hw + 262144;
    _Float16* w32c  = hw + 327680;
    _Float16* w41c  = hw + 393216;   // 131072
    _Float16* w42c  = hw + 524288;   // 262144
    _Float16* sw1c  = hw + 786432;   // 131072
    _Float16* sw2c  = hw + 917504;   // 262144
    _Float16* scw1c = hw + 1179648;  // 131072
    _Float16* scw2c = hw + 1310720;  // 262144
    _Float16* bia   = hw + 1572864;
    _Float16* b12 = bia, *b22 = bia + 256, *b32 = bia + 512;
    _Float16* b42 = bia + 768, *sb2 = bia + 1280, *scb2 = bia + 1792;

    CW cw;
    const float* wsrc[12] = {fin[1], fin[2], fin[4], fin[5], fin[7], fin[8],
                             fin[10], fin[11], fin[13], fin[14], fin[16], fin[17]};
    _Float16* wdst[12]    = {w11c, w12c, w21c, w22c, w31c, w32c,
                             w41c, w42c, sw1c, sw2c, scw1c, scw2c};
    const int wR[12] = {256,256,256,256,256,256, 512,512,512,512,512,512};
    const int wK[12] = {256,256,256,256,256,256, 256,512,256,512,256,512};
    for (int i = 0; i < 12; ++i) {
        cw.s[i] = wsrc[i]; cw.d[i] = (h8*)wdst[i]; cw.R[i] = wR[i]; cw.K[i] = wK[i];
    }
    CB cb;
    const float* bsrc[6] = {fin[3], fin[6], fin[9], fin[12], fin[15], fin[18]};
    _Float16* bdst[6]    = {b12, b22, b32, b42, sb2, scb2};
    const int bn[6]      = {256, 256, 256, 512, 512, 512};
    for (int i = 0; i < 6; ++i) { cb.s[i] = bsrc[i]; cb.d[i] = bdst[i]; cb.n[i] = bn[i]; }

    NetP p;
    p.x   = fin[0];
    p.w11 = (const h8*)w11c; p.w12 = (const h8*)w12c;
    p.w21 = (const h8*)w21c; p.w22 = (const h8*)w22c;
    p.w31 = (const h8*)w31c; p.w32 = (const h8*)w32c;
    p.w41 = (const h8*)w41c; p.w42 = (const h8*)w42c;
    p.sw1 = (const h8*)sw1c; p.sw2 = (const h8*)sw2c;
    p.scw1 = (const h8*)scw1c; p.scw2 = (const h8*)scw2c;
    p.b12 = b12; p.b22 = b22; p.b32 = b32; p.b42 = b42; p.sb2 = sb2; p.scb2 = scb2;
    p.out = (float*)d_out;

    cvtw<<<dim3(64, 12), 256, 0, stream>>>(cw);
    cvtb<<<1, 256, 0, stream>>>(cb);
    netf<<<dim3(256), 512, 0, stream>>>(p);
}

// Round 14
// 79.847 us; speedup vs baseline: 1.5562x; 1.5562x over previous
//
#include <hip/hip_runtime.h>
#include <math.h>

// Tropical bottleneck network — fully fused single kernel (R12 dataflow),
// re-geared for TLP: 256 blocks x 1024 threads (16 waves = 4/SIMD per CU),
// same per-block work and W traffic as R12's proven 91 us kernel.
// Each block owns 4 batch cols; 12 stages locally with __syncthreads().
// Activations in LDS [K][4] f16; weights pre-chunked Wc[K/8][R][8] f16 in L2.
// Stage: lane = row-group (W coalesced 16B), x broadcast from LDS,
// 2 rows/thread, KS-way K-split (KS = 1024/(R/2)) + LDS partial combine.

typedef _Float16 h2 __attribute__((ext_vector_type(2)));
typedef _Float16 h8 __attribute__((ext_vector_type(8)));

template<int M> __device__ __forceinline__ h2 rdv(h2 a, h2 b) {
    if constexpr (M) return __builtin_elementwise_max(a, b);
    else             return __builtin_elementwise_min(a, b);
}

struct NetP {
    const float* x;
    const h8 *w11, *w12, *w21, *w22, *w31, *w32;
    const h8 *w41, *w42, *sw1, *sw2, *scw1, *scw2;
    const _Float16 *b12, *b22, *b32, *b42, *sb2, *scb2;
    float* out;
};

// One semiring stage on this block's 4 batch cols.
// X: LDS [K][4] halfs. Y: LDS [R][4] (or global f32 out if GOUT).
template<int ISMAX, int R, int K, bool GOUT>
__device__ __forceinline__ void stage(
    const h8* __restrict__ Wc,          // global chunked [K/8][R]
    const _Float16* __restrict__ bias,  // global f16 (ISMAX) or nullptr
    const _Float16* __restrict__ X,
    const _Float16* __restrict__ E1,    // LDS min-combine or nullptr
    const _Float16* __restrict__ E2,    // LDS max-combine or nullptr
    _Float16* __restrict__ Y,
    float* __restrict__ gout, int b0,
    h2* __restrict__ part)
{
    constexpr int NRG = R / 2;               // row-groups (2 rows/thread)
    constexpr int KS  = 1024 / NRG;          // K-split ways (8 or 4)
    static_assert(NRG * KS == 1024, "thread mapping");
    const int tid  = threadIdx.x;
    const int rowg = tid & (NRG - 1);
    const int kq   = tid / NRG;              // wave-uniform (NRG multiple of 64)
    const int r0 = rowg, r1 = rowg + NRG;
    constexpr int NC = (K / KS) / 8;         // chunks per thread
    const int kc0 = kq * NC;

    const h2* Xh2 = (const h2*)X;

    h2 a00, a01, a10, a11;
    {   // peel first chunk (init, no +-INF)
        h8 w0 = Wc[(size_t)kc0 * R + r0];
        h8 w1 = Wc[(size_t)kc0 * R + r1];
        const h2* xk = Xh2 + kc0 * 16;
        h2 xs0 = xk[0], xs1 = xk[1];
        h2 u = {w0[0], w0[0]}, v = {w1[0], w1[0]};
        a00 = xs0 + u; a01 = xs1 + u;
        a10 = xs0 + v; a11 = xs1 + v;
#pragma unroll
        for (int j = 1; j < 8; ++j) {
            xs0 = xk[2 * j]; xs1 = xk[2 * j + 1];
            h2 uu = {w0[j], w0[j]}, vv = {w1[j], w1[j]};
            a00 = rdv<ISMAX>(a00, xs0 + uu); a01 = rdv<ISMAX>(a01, xs1 + uu);
            a10 = rdv<ISMAX>(a10, xs0 + vv); a11 = rdv<ISMAX>(a11, xs1 + vv);
        }
    }
#pragma unroll 2
    for (int kc = kc0 + 1; kc < kc0 + NC; ++kc) {
        h8 w0 = Wc[(size_t)kc * R + r0];
        h8 w1 = Wc[(size_t)kc * R + r1];
        const h2* xk = Xh2 + kc * 16;
#pragma unroll
        for (int j = 0; j < 8; ++j) {
            h2 xs0 = xk[2 * j], xs1 = xk[2 * j + 1];
            h2 uu = {w0[j], w0[j]}, vv = {w1[j], w1[j]};
            a00 = rdv<ISMAX>(a00, xs0 + uu); a01 = rdv<ISMAX>(a01, xs1 + uu);
            a10 = rdv<ISMAX>(a10, xs0 + vv); a11 = rdv<ISMAX>(a11, xs1 + vv);
        }
    }

    if (kq) {
        h2* pp = part + (size_t)(kq - 1) * R * 2;
        pp[r0 * 2] = a00; pp[r0 * 2 + 1] = a01;
        pp[r1 * 2] = a10; pp[r1 * 2 + 1] = a11;
    }
    __syncthreads();
    if (kq == 0) {
#pragma unroll
        for (int qq = 0; qq < KS - 1; ++qq) {
            const h2* pp = part + (size_t)qq * R * 2;
            a00 = rdv<ISMAX>(a00, pp[r0 * 2]); a01 = rdv<ISMAX>(a01, pp[r0 * 2 + 1]);
            a10 = rdv<ISMAX>(a10, pp[r1 * 2]); a11 = rdv<ISMAX>(a11, pp[r1 * 2 + 1]);
        }
        if (ISMAX) {
            _Float16 q0 = bias[r0], q1 = bias[r1];
            h2 s0 = {q0, q0}, s1 = {q1, q1};
            a00 += s0; a01 += s0; a10 += s1; a11 += s1;
        }
        if (E1) {
            const h2* e = (const h2*)E1;
            a00 = __builtin_elementwise_min(a00, e[r0 * 2]);
            a01 = __builtin_elementwise_min(a01, e[r0 * 2 + 1]);
            a10 = __builtin_elementwise_min(a10, e[r1 * 2]);
            a11 = __builtin_elementwise_min(a11, e[r1 * 2 + 1]);
        }
        if (E2) {
            const h2* e = (const h2*)E2;
            a00 = __builtin_elementwise_max(a00, e[r0 * 2]);
            a01 = __builtin_elementwise_max(a01, e[r0 * 2 + 1]);
            a10 = __builtin_elementwise_max(a10, e[r1 * 2]);
            a11 = __builtin_elementwise_max(a11, e[r1 * 2 + 1]);
        }
        if constexpr (GOUT) {
            gout[(size_t)(b0 + 0) * 512 + r0] = (float)a00[0];
            gout[(size_t)(b0 + 1) * 512 + r0] = (float)a00[1];
            gout[(size_t)(b0 + 2) * 512 + r0] = (float)a01[0];
            gout[(size_t)(b0 + 3) * 512 + r0] = (float)a01[1];
            gout[(size_t)(b0 + 0) * 512 + r1] = (float)a10[0];
            gout[(size_t)(b0 + 1) * 512 + r1] = (float)a10[1];
            gout[(size_t)(b0 + 2) * 512 + r1] = (float)a11[0];
            gout[(size_t)(b0 + 3) * 512 + r1] = (float)a11[1];
        } else {
            h2* y = (h2*)Y;
            y[r0 * 2] = a00; y[r0 * 2 + 1] = a01;
            y[r1 * 2] = a10; y[r1 * 2 + 1] = a11;
        }
    }
    __syncthreads();
}

__global__ __launch_bounds__(1024) void netf(NetP p)
{
    __shared__ __align__(16) _Float16 X0[256 * 4];               // 2 KB
    __shared__ __align__(16) _Float16 B0[512 * 4], B1[512 * 4];  // 4 KB each
    __shared__ __align__(16) _Float16 B2[512 * 4], B3[512 * 4];
    __shared__ __align__(16) h2 part[3584];                      // 14 KB
    const int tid = threadIdx.x;
    const int b0  = blockIdx.x * 4;

    {   // load x f32 -> X0 f16 [k][4b], one value per thread
        const int bl = tid >> 8;          // 0..3
        const int k  = tid & 255;
        X0[k * 4 + bl] = (_Float16)p.x[(size_t)(b0 + bl) * 256 + k];
    }
    __syncthreads();

    float* o = p.out;
    // bottleneck shortcut first (keeps X0 live only through layer 1)
    stage<0,512,256,false>(p.scw1, nullptr, X0, nullptr, nullptr, B0, o, b0, part);
    stage<1,512,512,false>(p.scw2, p.scb2,  B0, nullptr, nullptr, B1, o, b0, part); // B1=SCout
    // layer 1
    stage<0,256,256,false>(p.w11, nullptr, X0, nullptr, nullptr, B0, o, b0, part);
    stage<1,256,256,false>(p.w12, p.b12,   B0, X0,      nullptr, B2, o, b0, part);
    // layer 2
    stage<0,256,256,false>(p.w21, nullptr, B2, nullptr, nullptr, B0, o, b0, part);
    stage<1,256,256,false>(p.w22, p.b22,   B0, B2,      nullptr, B3, o, b0, part);
    // layer 3
    stage<0,256,256,false>(p.w31, nullptr, B3, nullptr, nullptr, B0, o, b0, part);
    stage<1,256,256,false>(p.w32, p.b32,   B0, B3,      nullptr, B2, o, b0, part);  // B2=x3
    // layer 4
    stage<0,512,256,false>(p.w41, nullptr, B2, nullptr, nullptr, B0, o, b0, part);  // T1
    stage<0,512,256,false>(p.sw1, nullptr, B2, nullptr, nullptr, B3, o, b0, part);  // T2
    stage<1,512,512,false>(p.w42, p.b42,   B0, nullptr, nullptr, B2, o, b0, part);  // O4
    // final: max(min(maxbplus(T2,sw2,sb2), O4), SCout) -> global out
    stage<1,512,512,true >(p.sw2, p.sb2,   B3, B2,      B1, nullptr, o, b0, part);
}

// ---- one-time prep: weights f32 [R][K] -> f16 chunked Wc[K/8][R][8]; biases f32->f16 ----
struct Prep {
    const float* s[12]; h8* d[12]; int R[12]; int K[12];
    const float* bs[6]; _Float16* bd[6]; int bn[6];
};
__global__ __launch_bounds__(256) void cvtw(Prep p)
{
    const int m = blockIdx.y;
    if (m == 12) {                        // bias slice
        if (blockIdx.x != 0) return;
        for (int s = 0; s < 6; ++s)
            for (int i = threadIdx.x; i < p.bn[s]; i += 256)
                p.bd[s][i] = (_Float16)p.bs[s][i];
        return;
    }
    const int R = p.R[m], K = p.K[m];
    const int tilesR = R >> 6;
    const int nt = tilesR * (K >> 6);
    const int t = blockIdx.x;
    if (t >= nt) return;
    const int tr = t % tilesR, tk = t / tilesR;

    __shared__ float s[64][65];
    const int lane = threadIdx.x & 63, ty = threadIdx.x >> 6;
    const float* src = p.s[m];
#pragma unroll
    for (int r = ty; r < 64; r += 4)
        s[r][lane] = src[(size_t)(tr * 64 + r) * K + tk * 64 + lane];
    __syncthreads();
    h8* dst = p.d[m];
#pragma unroll
    for (int c = 0; c < 2; ++c) {
        int cc = ty + c * 4;                 // 0..7
        h8 v;
#pragma unroll
        for (int j = 0; j < 8; ++j) v[j] = (_Float16)s[lane][cc * 8 + j];
        dst[(size_t)(tk * 8 + cc) * R + tr * 64 + lane] = v;
    }
}

extern "C" void kernel_launch(void* const* d_in, const int* in_sizes, int n_in,
                              void* d_out, int out_size, void* d_ws, size_t ws_size,
                              hipStream_t stream) {
    (void)in_sizes; (void)n_in; (void)ws_size; (void)out_size;
    const float* fin[19];
    for (int i = 0; i < 19; ++i) fin[i] = (const float*)d_in[i];

    _Float16* hw = (_Float16*)d_ws;

    // chunked f16 weights in ws (halfs); offsets multiples of 8 (16B aligned)
    _Float16* w11c  = hw;
    _Float16* w12c  = hw + 65536;
    _Float16* w21c  = hw + 131072;
    _Float16* w22c  = hw + 196608;
    _Float16* w31c  = hw + 262144;
    _Float16* w32c  = hw + 327680;
    _Float16* w41c  = hw + 393216;   // 131072
    _Float16* w42c  = hw + 524288;   // 262144
    _Float16* sw1c  = hw + 786432;   // 131072
    _Float16* sw2c  = hw + 917504;   // 262144
    _Float16* scw1c = hw + 1179648;  // 131072
    _Float16* scw2c = hw + 1310720;  // 262144
    _Float16* bia   = hw + 1572864;
    _Float16* b12 = bia, *b22 = bia + 256, *b32 = bia + 512;
    _Float16* b42 = bia + 768, *sb2 = bia + 1280, *scb2 = bia + 1792;

    Prep cw;
    const float* wsrc[12] = {fin[1], fin[2], fin[4], fin[5], fin[7], fin[8],
                             fin[10], fin[11], fin[13], fin[14], fin[16], fin[17]};
    _Float16* wdst[12]    = {w11c, w12c, w21c, w22c, w31c, w32c,
                             w41c, w42c, sw1c, sw2c, scw1c, scw2c};
    const int wR[12] = {256,256,256,256,256,256, 512,512,512,512,512,512};
    const int wK[12] = {256,256,256,256,256,256, 256,512,256,512,256,512};
    for (int i = 0; i < 12; ++i) {
        cw.s[i] = wsrc[i]; cw.d[i] = (h8*)wdst[i]; cw.R[i] = wR[i]; cw.K[i] = wK[i];
    }
    const float* bsrc[6] = {fin[3], fin[6], fin[9], fin[12], fin[15], fin[18]};
    _Float16* bdst[6]    = {b12, b22, b32, b42, sb2, scb2};
    const int bn[6]      = {256, 256, 256, 512, 512, 512};
    for (int i = 0; i < 6; ++i) { cw.bs[i] = bsrc[i]; cw.bd[i] = bdst[i]; cw.bn[i] = bn[i]; }

    NetP p;
    p.x   = fin[0];
    p.w11 = (const h8*)w11c; p.w12 = (const h8*)w12c;
    p.w21 = (const h8*)w21c; p.w22 = (const h8*)w22c;
    p.w31 = (const h8*)w31c; p.w32 = (const h8*)w32c;
    p.w41 = (const h8*)w41c; p.w42 = (const h8*)w42c;
    p.sw1 = (const h8*)sw1c; p.sw2 = (const h8*)sw2c;
    p.scw1 = (const h8*)scw1c; p.scw2 = (const h8*)scw2c;
    p.b12 = b12; p.b22 = b22; p.b32 = b32; p.b42 = b42; p.sb2 = sb2; p.scb2 = scb2;
    p.out = (float*)d_out;

    cvtw<<<dim3(64, 13), 256, 0, stream>>>(cw);
    netf<<<dim3(256), dim3(1024), 0, stream>>>(p);
}

// Round 15
// 78.634 us; speedup vs baseline: 1.5802x; 1.0154x over previous
//
#include <hip/hip_runtime.h>
#include <math.h>

// Tropical bottleneck network — fully fused (R12/R14 dataflow), occupancy-max:
// 512 blocks x 1024 threads, 2 batch cols per block -> 2 blocks/CU,
// 32 waves/CU (8/SIMD). Each block runs all 12 stages on its 2 cols with
// local barriers; co-resident blocks hide each other's W-latency/barriers.
// Activations in LDS [K][2] f16; weights pre-chunked Wc[K/8][R][8] f16 (L2).
// Stage: lane = row-group, 2 rows/thread, KS-way K-split + LDS combine.

typedef _Float16 h2 __attribute__((ext_vector_type(2)));
typedef _Float16 h8 __attribute__((ext_vector_type(8)));

template<int M> __device__ __forceinline__ h2 rdv(h2 a, h2 b) {
    if constexpr (M) return __builtin_elementwise_max(a, b);
    else             return __builtin_elementwise_min(a, b);
}

struct NetP {
    const float* x;
    const h8 *w11, *w12, *w21, *w22, *w31, *w32;
    const h8 *w41, *w42, *sw1, *sw2, *scw1, *scw2;
    const _Float16 *b12, *b22, *b32, *b42, *sb2, *scb2;
    float* out;
};

// One semiring stage on this block's 2 batch cols.
// X: LDS [K][2] halfs. Y: LDS [R][2] (or global f32 out if GOUT).
template<int ISMAX, int R, int K, bool GOUT>
__device__ __forceinline__ void stage(
    const h8* __restrict__ Wc,          // global chunked [K/8][R]
    const _Float16* __restrict__ bias,  // global f16 (ISMAX) or nullptr
    const _Float16* __restrict__ X,
    const _Float16* __restrict__ E1,    // LDS min-combine or nullptr
    const _Float16* __restrict__ E2,    // LDS max-combine or nullptr
    _Float16* __restrict__ Y,
    float* __restrict__ gout, int b0,
    h2* __restrict__ part)
{
    constexpr int NRG = R / 2;               // row-groups (2 rows/thread)
    constexpr int KS  = 1024 / NRG;          // K-split ways (8 or 4)
    static_assert(NRG * KS == 1024, "thread mapping");
    const int tid  = threadIdx.x;
    const int rowg = tid & (NRG - 1);
    const int kq   = tid / NRG;              // wave-uniform (NRG multiple of 64)
    const int r0 = rowg, r1 = rowg + NRG;
    constexpr int NC = (K / 8) / KS;         // chunks per thread
    const int kc0 = kq * NC;

    const h2* Xh2 = (const h2*)X;            // 1 h2 per k (2 cols)

    h2 a0, a1;
    {   // peel first chunk (init, no +-INF)
        h8 w0 = Wc[(size_t)kc0 * R + r0];
        h8 w1 = Wc[(size_t)kc0 * R + r1];
        const h2* xk = Xh2 + kc0 * 8;
        h2 xs = xk[0];
        h2 u = {w0[0], w0[0]}, v = {w1[0], w1[0]};
        a0 = xs + u; a1 = xs + v;
#pragma unroll
        for (int j = 1; j < 8; ++j) {
            xs = xk[j];
            h2 uu = {w0[j], w0[j]}, vv = {w1[j], w1[j]};
            a0 = rdv<ISMAX>(a0, xs + uu);
            a1 = rdv<ISMAX>(a1, xs + vv);
        }
    }
#pragma unroll 2
    for (int kc = kc0 + 1; kc < kc0 + NC; ++kc) {
        h8 w0 = Wc[(size_t)kc * R + r0];
        h8 w1 = Wc[(size_t)kc * R + r1];
        const h2* xk = Xh2 + kc * 8;
#pragma unroll
        for (int j = 0; j < 8; ++j) {
            h2 xs = xk[j];
            h2 uu = {w0[j], w0[j]}, vv = {w1[j], w1[j]};
            a0 = rdv<ISMAX>(a0, xs + uu);
            a1 = rdv<ISMAX>(a1, xs + vv);
        }
    }

    if (kq) {
        h2* pp = part + (size_t)(kq - 1) * R;
        pp[r0] = a0; pp[r1] = a1;
    }
    __syncthreads();
    if (kq == 0) {
#pragma unroll
        for (int qq = 0; qq < KS - 1; ++qq) {
            const h2* pp = part + (size_t)qq * R;
            a0 = rdv<ISMAX>(a0, pp[r0]);
            a1 = rdv<ISMAX>(a1, pp[r1]);
        }
        if (ISMAX) {
            _Float16 q0 = bias[r0], q1 = bias[r1];
            h2 s0 = {q0, q0}, s1 = {q1, q1};
            a0 += s0; a1 += s1;
        }
        if (E1) {
            const h2* e = (const h2*)E1;
            a0 = __builtin_elementwise_min(a0, e[r0]);
            a1 = __builtin_elementwise_min(a1, e[r1]);
        }
        if (E2) {
            const h2* e = (const h2*)E2;
            a0 = __builtin_elementwise_max(a0, e[r0]);
            a1 = __builtin_elementwise_max(a1, e[r1]);
        }
        if constexpr (GOUT) {
            gout[(size_t)(b0 + 0) * 512 + r0] = (float)a0[0];
            gout[(size_t)(b0 + 1) * 512 + r0] = (float)a0[1];
            gout[(size_t)(b0 + 0) * 512 + r1] = (float)a1[0];
            gout[(size_t)(b0 + 1) * 512 + r1] = (float)a1[1];
        } else {
            h2* y = (h2*)Y;
            y[r0] = a0; y[r1] = a1;
        }
    }
    __syncthreads();
}

__global__ __launch_bounds__(1024) void netf(NetP p)
{
    __shared__ __align__(16) _Float16 X0[256 * 2];               // 1 KB
    __shared__ __align__(16) _Float16 B0[512 * 2], B1[512 * 2];  // 2 KB each
    __shared__ __align__(16) _Float16 B2[512 * 2], B3[512 * 2];
    __shared__ __align__(16) h2 part[1792];                      // 7 KB
    const int tid = threadIdx.x;
    const int b0  = blockIdx.x * 2;

    if (tid < 512) {   // x f32 -> X0 f16 [k][2b]
        const int bl = tid >> 8;          // 0..1
        const int k  = tid & 255;
        X0[k * 2 + bl] = (_Float16)p.x[(size_t)(b0 + bl) * 256 + k];
    }
    __syncthreads();

    float* o = p.out;
    // bottleneck shortcut first (keeps X0 live only through layer 1)
    stage<0,512,256,false>(p.scw1, nullptr, X0, nullptr, nullptr, B0, o, b0, part);
    stage<1,512,512,false>(p.scw2, p.scb2,  B0, nullptr, nullptr, B1, o, b0, part); // B1=SCout
    // layer 1
    stage<0,256,256,false>(p.w11, nullptr, X0, nullptr, nullptr, B0, o, b0, part);
    stage<1,256,256,false>(p.w12, p.b12,   B0, X0,      nullptr, B2, o, b0, part);
    // layer 2
    stage<0,256,256,false>(p.w21, nullptr, B2, nullptr, nullptr, B0, o, b0, part);
    stage<1,256,256,false>(p.w22, p.b22,   B0, B2,      nullptr, B3, o, b0, part);
    // layer 3
    stage<0,256,256,false>(p.w31, nullptr, B3, nullptr, nullptr, B0, o, b0, part);
    stage<1,256,256,false>(p.w32, p.b32,   B0, B3,      nullptr, B2, o, b0, part);  // B2=x3
    // layer 4
    stage<0,512,256,false>(p.w41, nullptr, B2, nullptr, nullptr, B0, o, b0, part);  // T1
    stage<0,512,256,false>(p.sw1, nullptr, B2, nullptr, nullptr, B3, o, b0, part);  // T2
    stage<1,512,512,false>(p.w42, p.b42,   B0, nullptr, nullptr, B2, o, b0, part);  // O4
    // final: max(min(maxbplus(T2,sw2,sb2), O4), SCout) -> global out
    stage<1,512,512,true >(p.sw2, p.sb2,   B3, B2,      B1, nullptr, o, b0, part);
}

// ---- one-time prep: weights f32 [R][K] -> f16 chunked Wc[K/8][R][8]; biases f32->f16 ----
struct Prep {
    const float* s[12]; h8* d[12]; int R[12]; int K[12];
    const float* bs[6]; _Float16* bd[6]; int bn[6];
};
__global__ __launch_bounds__(256) void cvtw(Prep p)
{
    const int m = blockIdx.y;
    if (m == 12) {                        // bias slice
        if (blockIdx.x != 0) return;
        for (int s = 0; s < 6; ++s)
            for (int i = threadIdx.x; i < p.bn[s]; i += 256)
                p.bd[s][i] = (_Float16)p.bs[s][i];
        return;
    }
    const int R = p.R[m], K = p.K[m];
    const int tilesR = R >> 6;
    const int nt = tilesR * (K >> 6);
    const int t = blockIdx.x;
    if (t >= nt) return;
    const int tr = t % tilesR, tk = t / tilesR;

    __shared__ float s[64][65];
    const int lane = threadIdx.x & 63, ty = threadIdx.x >> 6;
    const float* src = p.s[m];
#pragma unroll
    for (int r = ty; r < 64; r += 4)
        s[r][lane] = src[(size_t)(tr * 64 + r) * K + tk * 64 + lane];
    __syncthreads();
    h8* dst = p.d[m];
#pragma unroll
    for (int c = 0; c < 2; ++c) {
        int cc = ty + c * 4;                 // 0..7
        h8 v;
#pragma unroll
        for (int j = 0; j < 8; ++j) v[j] = (_Float16)s[lane][cc * 8 + j];
        dst[(size_t)(tk * 8 + cc) * R + tr * 64 + lane] = v;
    }
}

extern "C" void kernel_launch(void* const* d_in, const int* in_sizes, int n_in,
                              void* d_out, int out_size, void* d_ws, size_t ws_size,
                              hipStream_t stream) {
    (void)in_sizes; (void)n_in; (void)ws_size; (void)out_size;
    const float* fin[19];
    for (int i = 0; i < 19; ++i) fin[i] = (const float*)d_in[i];

    _Float16* hw = (_Float16*)d_ws;

    _Float16* w11c  = hw;
    _Float16* w12c  = hw + 65536;
    _Float16* w21c  = hw + 131072;
    _Float16* w22c  = hw + 196608;
    _Float16* w31c  = hw + 262144;
    _Float16* w32c  = hw + 327680;
    _Float16* w41c  = hw + 393216;   // 131072
    _Float16* w42c  = hw + 524288;   // 262144
    _Float16* sw1c  = hw + 786432;   // 131072
    _Float16* sw2c  = hw + 917504;   // 262144
    _Float16* scw1c = hw + 1179648;  // 131072
    _Float16* scw2c = hw + 1310720;  // 262144
    _Float16* bia   = hw + 1572864;
    _Float16* b12 = bia, *b22 = bia + 256, *b32 = bia + 512;
    _Float16* b42 = bia + 768, *sb2 = bia + 1280, *scb2 = bia + 1792;

    Prep cw;
    const float* wsrc[12] = {fin[1], fin[2], fin[4], fin[5], fin[7], fin[8],
                             fin[10], fin[11], fin[13], fin[14], fin[16], fin[17]};
    _Float16* wdst[12]    = {w11c, w12c, w21c, w22c, w31c, w32c,
                             w41c, w42c, sw1c, sw2c, scw1c, scw2c};
    const int wR[12] = {256,256,256,256,256,256, 512,512,512,512,512,512};
    const int wK[12] = {256,256,256,256,256,256, 256,512,256,512,256,512};
    for (int i = 0; i < 12; ++i) {
        cw.s[i] = wsrc[i]; cw.d[i] = (h8*)wdst[i]; cw.R[i] = wR[i]; cw.K[i] = wK[i];
    }
    const float* bsrc[6] = {fin[3], fin[6], fin[9], fin[12], fin[15], fin[18]};
    _Float16* bdst[6]    = {b12, b22, b32, b42, sb2, scb2};
    const int bn[6]      = {256, 256, 256, 512, 512, 512};
    for (int i = 0; i < 6; ++i) { cw.bs[i] = bsrc[i]; cw.bd[i] = bdst[i]; cw.bn[i] = bn[i]; }

    NetP p;
    p.x   = fin[0];
    p.w11 = (const h8*)w11c; p.w12 = (const h8*)w12c;
    p.w21 = (const h8*)w21c; p.w22 = (const h8*)w22c;
    p.w31 = (const h8*)w31c; p.w32 = (const h8*)w32c;
    p.w41 = (const h8*)w41c; p.w42 = (const h8*)w42c;
    p.sw1 = (const h8*)sw1c; p.sw2 = (const h8*)sw2c;
    p.scw1 = (const h8*)scw1c; p.scw2 = (const h8*)scw2c;
    p.b12 = b12; p.b22 = b22; p.b32 = b32; p.b42 = b42; p.sb2 = sb2; p.scb2 = scb2;
    p.out = (float*)d_out;

    cvtw<<<dim3(64, 13), 256, 0, stream>>>(cw);
    netf<<<dim3(512), dim3(1024), 0, stream>>>(p);
}